// Round 13
// baseline (41.755 us; speedup 1.0000x reference)
//
#include <hip/hip_runtime.h>

// RejectionSampler: B=128 requests, S=8 draft tokens each, V=32000 vocab.
// Inputs (setup_inputs order):
//  0 target_logits [T*V] f32, 1 draft_probs [T*V] f32, 2 draft_token_ids [T] i32,
//  3 bonus_token_ids [B] i32, 4 temperature [B] f32, 5 uniform_probs [T] f32,
//  6 q [B*V] f32, 7 cu_num_draft_tokens [B] i32 (unused: uniform raggedness)
// Output: output_token_ids [B, S+1] int32.
//
// Division-free, max-free math (positive rescalings preserve decisions):
//   e = exp2(l * log2e/temp)   (|l*c| small for this data: no overflow)
//   accept:  e_t >= u*d_t*D,  D = sum e  (fixed reduction order, stored once)
//   argmax((e/D - d)/q) == argmax(e*rcp(q) - D*(d*rcp(q)))
//
// TWO dispatches (+1 tiny memset). K2 combines its 4 vocab-chunks per request
// with ATOMIC-ONLY message passing — all relaxed (no acquire/release: round-8
// lesson, ACQ_REL fences emit per-block L2 flushes = storm). Pattern:
//   chunk block:  atomic_max(w_best[b], packed)   [relaxed, agent]
//                 s_waitcnt vmcnt(0)               (max globally performed)
//                 old = fetch_add(w_cnt[b], 1)     [relaxed, agent]
//                 last arriver (old==3): atomic-load w_best, write output row
// packed = enc(bv)<<32 | ~bi  (enc = monotone float->uint32), so larger
// packed == larger bv, ties broken toward SMALLER index (jnp.argmax rule).
// Atomics execute at the device coherence point -> coherent across XCDs.

constexpr int PLACEHOLDER = -1;
constexpr int B = 128;
constexpr int S = 8;
constexpr int V = 32000;
constexpr int T = B * S;
constexpr int NV4 = V / 4;            // 8000 float4 per row
constexpr int CHUNKS = 4;
constexpr int CV4 = NV4 / CHUNKS;     // 2000 float4 per chunk
constexpr int K2T = 512;              // K2 threads per block

extern "C" __device__ float __builtin_amdgcn_exp2f(float);
extern "C" __device__ float __builtin_amdgcn_rcpf(float);

// -------- K1: per-token softmax denominator + accept bit --------
__global__ __launch_bounds__(512)
void k1_sum(const float* __restrict__ logits,
            const float* __restrict__ dprobs,
            const int*   __restrict__ draft_ids,
            const float* __restrict__ temperature,
            const float* __restrict__ uniform_probs,
            float* __restrict__ w_D,     // [T]
            int*   __restrict__ w_acc)   // [T]
{
    const int t   = blockIdx.x;
    const int tid = threadIdx.x, lane = tid & 63, wid = tid >> 6;  // 8 waves
    __shared__ float s_red[8];

    const float c = 1.4426950408889634f / temperature[t >> 3];
    const float4* lrow = (const float4*)(logits + (size_t)t * V);

    // thread-0 prefetch of accept-test scalars; cold-load latency hides
    // under the block's 128 KB stream below
    int dt = 0; float l_d = 0.f, d_d = 0.f, u = 0.f;
    if (tid == 0) {
        dt  = draft_ids[t];
        l_d = logits[(size_t)t * V + dt];
        d_d = dprobs[(size_t)t * V + dt];
        u   = uniform_probs[t];
    }

    float lsum = 0.f;
    #pragma unroll 4
    for (int j = 0; j < 16; ++j) {
        const int i4 = j * 512 + tid;
        if (i4 < NV4) {
            const float4 v = lrow[i4];
            lsum += (__builtin_amdgcn_exp2f(v.x * c) +
                     __builtin_amdgcn_exp2f(v.y * c)) +
                    (__builtin_amdgcn_exp2f(v.z * c) +
                     __builtin_amdgcn_exp2f(v.w * c));
        }
    }
    #pragma unroll
    for (int off = 32; off >= 1; off >>= 1)
        lsum += __shfl_xor(lsum, off, 64);
    if (lane == 0) s_red[wid] = lsum;
    __syncthreads();
    if (tid == 0) {
        const float D = ((s_red[0] + s_red[1]) + (s_red[2] + s_red[3])) +
                        ((s_red[4] + s_red[5]) + (s_red[6] + s_red[7]));
        w_D[t] = D;
        const float e_d = __builtin_amdgcn_exp2f(l_d * c);
        w_acc[t] = (d_d > 0.f) && (e_d >= u * d_d * D);
    }
}

// monotone float -> uint32 (total order matches float <; no NaNs here)
__device__ __forceinline__ unsigned int enc_f32(float f) {
    const unsigned int s = __float_as_uint(f);
    return ((int)s >= 0) ? (s | 0x80000000u) : ~s;
}

// -------- K2: chunked residual argmax + atomic combine + row write ----------
__global__ __launch_bounds__(K2T)
void k2_arg(const float* __restrict__ logits,
            const float* __restrict__ dprobs,
            const float* __restrict__ q,
            const float* __restrict__ temperature,
            const float* __restrict__ w_D,
            const int*   __restrict__ w_acc,
            const int*   __restrict__ draft_ids,
            const int*   __restrict__ bonus_ids,
            unsigned long long* __restrict__ w_best,  // [B], zeroed per call
            int* __restrict__ w_cnt,                  // [B], zeroed per call
            int* __restrict__ out)
{
    const int bid = blockIdx.x;
    const int b = bid >> 2, k = bid & 3;         // request, chunk
    const int tid = threadIdx.x, lane = tid & 63, wid = tid >> 6;  // 8 waves
    __shared__ float s_val[8];
    __shared__ int   s_idx[8];
    __shared__ int   s_needp;

    if (tid == 0) {
        int np = S;
        #pragma unroll
        for (int p = S - 1; p >= 0; --p)
            if (!w_acc[b * S + p]) np = p;
        s_needp = np;
    }
    __syncthreads();
    const int need_p = s_needp;                  // block-uniform
    if (need_p >= S) {                           // all accepted: no argmax
        if (k == 0 && tid == 0) {
            #pragma unroll
            for (int p = 0; p < S; ++p)
                out[b * (S + 1) + p] = draft_ids[b * S + p];
            out[b * (S + 1) + S] = bonus_ids[b];
        }
        return;
    }

    const int   t = b * S + need_p;
    const float c = 1.4426950408889634f / temperature[b];
    const float D = w_D[t];

    const float4* lrow = (const float4*)(logits + (size_t)t * V) + k * CV4;
    const float4* drow = (const float4*)(dprobs + (size_t)t * V) + k * CV4;
    const float4* qrow = (const float4*)(q      + (size_t)b * V) + k * CV4;

    // 12 batched float4 loads (high MLP), then register compute
    float4 lv[4], dv[4], qv[4];
    #pragma unroll
    for (int j = 0; j < 4; ++j) {
        const int i = j * K2T + tid;
        if (i < CV4) lv[j] = lrow[i];
    }
    #pragma unroll
    for (int j = 0; j < 4; ++j) {
        const int i = j * K2T + tid;
        if (i < CV4) dv[j] = drow[i];
    }
    #pragma unroll
    for (int j = 0; j < 4; ++j) {
        const int i = j * K2T + tid;
        if (i < CV4) qv[j] = qrow[i];
    }

    float bestv = -__builtin_inff();
    int   besti = 0x7fffffff;

#define RS_COMP(LC, DC, QC, GIDX)                                          \
    {                                                                      \
        const float e  = __builtin_amdgcn_exp2f((LC) * c);                 \
        const float rq = __builtin_amdgcn_rcpf(QC);                        \
        const float r  = fmaf(-((DC) * rq), D, e * rq);                    \
        if (r > bestv) { bestv = r; besti = (GIDX); }                      \
    }

    #pragma unroll
    for (int j = 0; j < 4; ++j) {
        const int i = j * K2T + tid;
        if (i < CV4) {
            const int base = (k * CV4 + i) * 4;   // global vocab index
            RS_COMP(lv[j].x, dv[j].x, qv[j].x, base + 0)
            RS_COMP(lv[j].y, dv[j].y, qv[j].y, base + 1)
            RS_COMP(lv[j].z, dv[j].z, qv[j].z, base + 2)
            RS_COMP(lv[j].w, dv[j].w, qv[j].w, base + 3)
        }
    }
#undef RS_COMP

    #pragma unroll
    for (int off = 32; off >= 1; off >>= 1) {
        const float ov = __shfl_xor(bestv, off, 64);
        const int   oi = __shfl_xor(besti, off, 64);
        if (ov > bestv || (ov == bestv && oi < besti)) { bestv = ov; besti = oi; }
    }
    if (lane == 0) { s_val[wid] = bestv; s_idx[wid] = besti; }
    __syncthreads();
    if (tid == 0) {
        float bv = s_val[0]; int bi = s_idx[0];
        #pragma unroll
        for (int w = 1; w < 8; ++w) {
            const float ov = s_val[w]; const int oi = s_idx[w];
            if (ov > bv || (ov == bv && oi < bi)) { bv = ov; bi = oi; }
        }
        // packed candidate: larger bv wins; tie -> smaller index wins
        const unsigned long long packed =
            ((unsigned long long)enc_f32(bv) << 32) |
            (unsigned int)(~(unsigned int)bi);
        __hip_atomic_fetch_max(&w_best[b], packed, __ATOMIC_RELAXED,
                               __HIP_MEMORY_SCOPE_AGENT);
        // ensure the max is globally performed before the counter bump
        asm volatile("s_waitcnt vmcnt(0)" ::: "memory");
        const int old = __hip_atomic_fetch_add(&w_cnt[b], 1, __ATOMIC_RELAXED,
                                               __HIP_MEMORY_SCOPE_AGENT);
        if (old == CHUNKS - 1) {
            // last arriver: all 4 maxes are globally visible (each preceded
            // its counter bump; bumps serialized at the coherence point)
            const unsigned long long fin =
                __hip_atomic_load(&w_best[b], __ATOMIC_RELAXED,
                                  __HIP_MEMORY_SCOPE_AGENT);
            const int rec = (int)(~(unsigned int)(fin & 0xFFFFFFFFull));
            #pragma unroll
            for (int p = 0; p < S; ++p) {
                int tok = PLACEHOLDER;
                if (p < need_p)       tok = draft_ids[b * S + p];
                else if (p == need_p) tok = rec;
                out[b * (S + 1) + p] = tok;
            }
            out[b * (S + 1) + S] = PLACEHOLDER;   // rejection => no bonus
        }
    }
}

extern "C" void kernel_launch(void* const* d_in, const int* in_sizes, int n_in,
                              void* d_out, int out_size, void* d_ws, size_t ws_size,
                              hipStream_t stream) {
    const float* logits      = (const float*)d_in[0];
    const float* dprobs      = (const float*)d_in[1];
    const int*   draft_ids   = (const int*)d_in[2];
    const int*   bonus_ids   = (const int*)d_in[3];
    const float* temperature = (const float*)d_in[4];
    const float* uniform     = (const float*)d_in[5];
    const float* q           = (const float*)d_in[6];
    // d_in[7] cu_num_draft_tokens unused (uniform S per request)

    int* out = (int*)d_out;
    float* w_D   = (float*)d_ws;                              // [T] (4 KB)
    int*   w_acc = (int*)(w_D + T);                           // [T] (4 KB)
    unsigned long long* w_best = (unsigned long long*)(w_acc + T);  // [B], 8B-aligned
    int*   w_cnt = (int*)(w_best + B);                        // [B]

    // zero w_best + w_cnt (1.5 KB, graph-capturable memset node)
    hipMemsetAsync(w_best, 0, B * sizeof(unsigned long long) + B * sizeof(int),
                   stream);

    k1_sum<<<T, 512, 0, stream>>>(logits, dprobs, draft_ids, temperature,
                                  uniform, w_D, w_acc);
    k2_arg<<<B * CHUNKS, K2T, 0, stream>>>(logits, dprobs, q, temperature,
                                           w_D, w_acc, draft_ids, bonus_ids,
                                           w_best, w_cnt, out);
}

// Round 14
// 36.460 us; speedup vs baseline: 1.1452x; 1.1452x over previous
//
#include <hip/hip_runtime.h>

// RejectionSampler: B=128 requests, S=8 draft tokens each, V=32000 vocab.
// Inputs (setup_inputs order):
//  0 target_logits [T*V] f32, 1 draft_probs [T*V] f32, 2 draft_token_ids [T] i32,
//  3 bonus_token_ids [B] i32, 4 temperature [B] f32, 5 uniform_probs [T] f32,
//  6 q [B*V] f32, 7 cu_num_draft_tokens [B] i32 (unused: uniform raggedness)
// Output: output_token_ids [B, S+1] int32.
//
// Division-free, max-free math (positive rescalings preserve decisions):
//   e = exp2(l * log2e/temp)   (|l*c| small for this data: no overflow)
//   accept:  e_t >= u*d_t*D,  D = sum e  (fixed reduction order, stored once)
//   argmax((e/D - d)/q) == argmax(e*rcp(q) - D*(d*rcp(q)))
//
// TWO dispatches, no memset. K2 spreads each request's argmax over 2 blocks
// (256 blocks = 1/CU, full machine). Pair combine uses RELAXED agent-scope
// atomics only (no acquire/release fences — round-8 lesson: ACQ_REL emits
// buffer_inv/wbl2 per block = L2-flush storm; relaxed sc1 ops are coherent
// per-instruction with no cache maintenance):
//   half-1: atomic-store candidate; s_waitcnt vmcnt(0); atomic-store flag=1
//   half-0: spin on flag (grid fully co-resident -> bounded), read candidate,
//           combine (tie keeps half-0 = smaller index = jnp.argmax rule),
//           write the 9-int output row.
// Flags are zeroed by K1 (plain stores; kernel boundary gives visibility).

constexpr int PLACEHOLDER = -1;
constexpr int B = 128;
constexpr int S = 8;
constexpr int V = 32000;
constexpr int T = B * S;
constexpr int NV4 = V / 4;            // 8000 float4 per row
constexpr int HV4 = NV4 / 2;          // 4000 float4 per half-row

extern "C" __device__ float __builtin_amdgcn_exp2f(float);
extern "C" __device__ float __builtin_amdgcn_rcpf(float);

// -------- K1: per-token softmax denominator + accept bit (+flag zero) -------
__global__ __launch_bounds__(512)
void k1_sum(const float* __restrict__ logits,
            const float* __restrict__ dprobs,
            const int*   __restrict__ draft_ids,
            const float* __restrict__ temperature,
            const float* __restrict__ uniform_probs,
            float* __restrict__ w_D,     // [T]
            int*   __restrict__ w_acc,   // [T]
            int*   __restrict__ w_flag)  // [B] zeroed here each call
{
    const int t   = blockIdx.x;
    const int tid = threadIdx.x, lane = tid & 63, wid = tid >> 6;  // 8 waves
    __shared__ float s_red[8];

    if (tid == 0 && t < B) w_flag[t] = 0;   // visible to K2 at kernel boundary

    const float c = 1.4426950408889634f / temperature[t >> 3];
    const float4* lrow = (const float4*)(logits + (size_t)t * V);

    // thread-0 prefetch of accept-test scalars; cold-load latency hides
    // under the block's 128 KB stream below
    int dt = 0; float l_d = 0.f, d_d = 0.f, u = 0.f;
    if (tid == 0) {
        dt  = draft_ids[t];
        l_d = logits[(size_t)t * V + dt];
        d_d = dprobs[(size_t)t * V + dt];
        u   = uniform_probs[t];
    }

    float lsum = 0.f;
    #pragma unroll 4
    for (int j = 0; j < 16; ++j) {
        const int i4 = j * 512 + tid;
        if (i4 < NV4) {
            const float4 v = lrow[i4];
            lsum += (__builtin_amdgcn_exp2f(v.x * c) +
                     __builtin_amdgcn_exp2f(v.y * c)) +
                    (__builtin_amdgcn_exp2f(v.z * c) +
                     __builtin_amdgcn_exp2f(v.w * c));
        }
    }
    #pragma unroll
    for (int off = 32; off >= 1; off >>= 1)
        lsum += __shfl_xor(lsum, off, 64);
    if (lane == 0) s_red[wid] = lsum;
    __syncthreads();
    if (tid == 0) {
        const float D = ((s_red[0] + s_red[1]) + (s_red[2] + s_red[3])) +
                        ((s_red[4] + s_red[5]) + (s_red[6] + s_red[7]));
        w_D[t] = D;
        const float e_d = __builtin_amdgcn_exp2f(l_d * c);
        w_acc[t] = (d_d > 0.f) && (e_d >= u * d_d * D);
    }
}

// ---- K2: half-vocab residual argmax; pair-combine via relaxed atomics ------
__global__ __launch_bounds__(512)
void k2_arg(const float* __restrict__ logits,
            const float* __restrict__ dprobs,
            const float* __restrict__ q,
            const float* __restrict__ temperature,
            const float* __restrict__ w_D,
            const int*   __restrict__ w_acc,
            const int*   __restrict__ draft_ids,
            const int*   __restrict__ bonus_ids,
            float* __restrict__ w_hbv,   // [B] half-1 candidate value
            int*   __restrict__ w_hbi,   // [B] half-1 candidate index
            int*   __restrict__ w_flag,  // [B] publish flag
            int*   __restrict__ out)
{
    const int bid = blockIdx.x;
    const int b = bid >> 1, h = bid & 1;          // request, half
    const int tid = threadIdx.x, lane = tid & 63, wid = tid >> 6;  // 8 waves
    __shared__ float s_val[8];
    __shared__ int   s_idx[8];
    __shared__ int   s_needp;

    if (tid == 0) {
        int np = S;
        #pragma unroll
        for (int p = S - 1; p >= 0; --p)
            if (!w_acc[b * S + p]) np = p;
        s_needp = np;
    }
    __syncthreads();
    const int need_p = s_needp;                   // block-uniform
    if (need_p >= S) {                            // all accepted: trivial row
        if (h == 0 && tid == 0) {
            #pragma unroll
            for (int p = 0; p < S; ++p)
                out[b * (S + 1) + p] = draft_ids[b * S + p];
            out[b * (S + 1) + S] = bonus_ids[b];
        }
        return;
    }

    const int   t = b * S + need_p;
    const float c = 1.4426950408889634f / temperature[b];
    const float D = w_D[t];

    const float4* lrow = (const float4*)(logits + (size_t)t * V) + h * HV4;
    const float4* drow = (const float4*)(dprobs + (size_t)t * V) + h * HV4;
    const float4* qrow = (const float4*)(q      + (size_t)b * V) + h * HV4;

    float bestv = -__builtin_inff();
    int   besti = 0x7fffffff;

#define RS_COMP(LC, DC, QC, GIDX)                                          \
    {                                                                      \
        const float e  = __builtin_amdgcn_exp2f((LC) * c);                 \
        const float rq = __builtin_amdgcn_rcpf(QC);                        \
        const float r  = fmaf(-((DC) * rq), D, e * rq);                    \
        if (r > bestv) { bestv = r; besti = (GIDX); }                      \
    }

    // 2 phases x 12 batched float4 loads (high MLP), then register compute
    #pragma unroll
    for (int ph = 0; ph < 2; ++ph) {
        float4 lv[4], dv[4], qv[4];
        #pragma unroll
        for (int j = 0; j < 4; ++j) {
            const int i = (ph * 4 + j) * 512 + tid;
            if (i < HV4) lv[j] = lrow[i];
        }
        #pragma unroll
        for (int j = 0; j < 4; ++j) {
            const int i = (ph * 4 + j) * 512 + tid;
            if (i < HV4) dv[j] = drow[i];
        }
        #pragma unroll
        for (int j = 0; j < 4; ++j) {
            const int i = (ph * 4 + j) * 512 + tid;
            if (i < HV4) qv[j] = qrow[i];
        }
        #pragma unroll
        for (int j = 0; j < 4; ++j) {
            const int i = (ph * 4 + j) * 512 + tid;
            if (i < HV4) {
                const int base = (h * HV4 + i) * 4;   // global vocab index
                RS_COMP(lv[j].x, dv[j].x, qv[j].x, base + 0)
                RS_COMP(lv[j].y, dv[j].y, qv[j].y, base + 1)
                RS_COMP(lv[j].z, dv[j].z, qv[j].z, base + 2)
                RS_COMP(lv[j].w, dv[j].w, qv[j].w, base + 3)
            }
        }
    }
#undef RS_COMP

    #pragma unroll
    for (int off = 32; off >= 1; off >>= 1) {
        const float ov = __shfl_xor(bestv, off, 64);
        const int   oi = __shfl_xor(besti, off, 64);
        if (ov > bestv || (ov == bestv && oi < besti)) { bestv = ov; besti = oi; }
    }
    if (lane == 0) { s_val[wid] = bestv; s_idx[wid] = besti; }
    __syncthreads();

    if (tid == 0) {
        float bv = s_val[0]; int bi = s_idx[0];
        #pragma unroll
        for (int w = 1; w < 8; ++w) {
            const float ov = s_val[w]; const int oi = s_idx[w];
            if (ov > bv || (ov == bv && oi < bi)) { bv = ov; bi = oi; }
        }
        if (h == 1) {
            // publish candidate, then flag; vmcnt(0) orders data before flag
            __hip_atomic_store(&w_hbv[b], bv, __ATOMIC_RELAXED,
                               __HIP_MEMORY_SCOPE_AGENT);
            __hip_atomic_store(&w_hbi[b], bi, __ATOMIC_RELAXED,
                               __HIP_MEMORY_SCOPE_AGENT);
            asm volatile("s_waitcnt vmcnt(0)" ::: "memory");
            __hip_atomic_store(&w_flag[b], 1, __ATOMIC_RELAXED,
                               __HIP_MEMORY_SCOPE_AGENT);
        } else {
            // consume partner candidate (bounded spin: pair co-resident)
            while (__hip_atomic_load(&w_flag[b], __ATOMIC_RELAXED,
                                     __HIP_MEMORY_SCOPE_AGENT) == 0)
                __builtin_amdgcn_s_sleep(2);
            const float pbv = __hip_atomic_load(&w_hbv[b], __ATOMIC_RELAXED,
                                                __HIP_MEMORY_SCOPE_AGENT);
            const int   pbi = __hip_atomic_load(&w_hbi[b], __ATOMIC_RELAXED,
                                                __HIP_MEMORY_SCOPE_AGENT);
            // half-1 indices are all larger: strict > keeps half-0 on ties
            if (pbv > bv) { bv = pbv; bi = pbi; }
            #pragma unroll
            for (int p = 0; p < S; ++p) {
                int tok = PLACEHOLDER;
                if (p < need_p)       tok = draft_ids[b * S + p];
                else if (p == need_p) tok = bi;
                out[b * (S + 1) + p] = tok;
            }
            out[b * (S + 1) + S] = PLACEHOLDER;   // rejection => no bonus
        }
    }
}

extern "C" void kernel_launch(void* const* d_in, const int* in_sizes, int n_in,
                              void* d_out, int out_size, void* d_ws, size_t ws_size,
                              hipStream_t stream) {
    const float* logits      = (const float*)d_in[0];
    const float* dprobs      = (const float*)d_in[1];
    const int*   draft_ids   = (const int*)d_in[2];
    const int*   bonus_ids   = (const int*)d_in[3];
    const float* temperature = (const float*)d_in[4];
    const float* uniform     = (const float*)d_in[5];
    const float* q           = (const float*)d_in[6];
    // d_in[7] cu_num_draft_tokens unused (uniform S per request)

    int* out = (int*)d_out;
    float* w_D    = (float*)d_ws;                 // [T]
    int*   w_acc  = (int*)(w_D + T);              // [T]
    float* w_hbv  = (float*)(w_acc + T);          // [B]
    int*   w_hbi  = (int*)(w_hbv + B);            // [B]
    int*   w_flag = w_hbi + B;                    // [B]

    k1_sum<<<T, 512, 0, stream>>>(logits, dprobs, draft_ids, temperature,
                                  uniform, w_D, w_acc, w_flag);
    k2_arg<<<2 * B, 512, 0, stream>>>(logits, dprobs, q, temperature,
                                      w_D, w_acc, draft_ids, bonus_ids,
                                      w_hbv, w_hbi, w_flag, out);
}